// Round 1
// baseline (942.342 us; speedup 1.0000x reference)
//
#include <hip/hip_runtime.h>
#include <math.h>

#define NN 100000
#define EE 1600000
#define GG 64
#define NCLS 10

// ---------------- CSR build ----------------

__global__ void hist_kernel(const int* __restrict__ dst, int* __restrict__ cnt, int n) {
    int e = blockIdx.x * 256 + threadIdx.x;
    if (e < n) atomicAdd(&cnt[dst[e]], 1);
}

// inclusive scan per 256-block; writes in-block inclusive to out1[i] (== rowptr+1), block total to bsum
__global__ void scanA_kernel(const int* __restrict__ in, int* __restrict__ out1,
                             int* __restrict__ bsum, int n) {
    __shared__ int s[256];
    int i = blockIdx.x * 256 + threadIdx.x;
    int v = (i < n) ? in[i] : 0;
    s[threadIdx.x] = v;
    __syncthreads();
    for (int off = 1; off < 256; off <<= 1) {
        int t = (threadIdx.x >= (unsigned)off) ? s[threadIdx.x - off] : 0;
        __syncthreads();
        s[threadIdx.x] += t;
        __syncthreads();
    }
    if (i < n) out1[i] = s[threadIdx.x];
    if (threadIdx.x == 255) bsum[blockIdx.x] = s[255];
}

// single-block exclusive scan of block sums (nb <= 512)
__global__ void scanB_kernel(int* __restrict__ bsum, int nb) {
    __shared__ int s[512];
    int v = (threadIdx.x < (unsigned)nb) ? bsum[threadIdx.x] : 0;
    s[threadIdx.x] = v;
    __syncthreads();
    for (int off = 1; off < 512; off <<= 1) {
        int t = (threadIdx.x >= (unsigned)off) ? s[threadIdx.x - off] : 0;
        __syncthreads();
        s[threadIdx.x] += t;
        __syncthreads();
    }
    if (threadIdx.x < (unsigned)nb) bsum[threadIdx.x] = s[threadIdx.x] - v;  // exclusive
}

__global__ void scanC_kernel(int* __restrict__ rowptr, const int* __restrict__ bsum, int n) {
    int i = blockIdx.x * 256 + threadIdx.x;
    if (i < n) rowptr[i + 1] += bsum[blockIdx.x];
    if (i == 0) rowptr[0] = 0;
}

__global__ void scatter_kernel(const int* __restrict__ src, const int* __restrict__ dst,
                               const int* __restrict__ rowptr, int* __restrict__ fill,
                               int* __restrict__ col, int n) {
    int e = blockIdx.x * 256 + threadIdx.x;
    if (e < n) {
        int d = dst[e];
        int p = rowptr[d] + atomicAdd(&fill[d], 1);
        col[p] = src[e];
    }
}

// ---------------- GEMM h = X @ W  (+ per-head attention logits) ----------------
// Block = 256 threads = 4 waves. Each wave: 64 lanes = 64 output cols, 4 rows/thread.
// Block covers 16 rows. W staged in LDS (K*64 floats).

template <int K>
__global__ __launch_bounds__(256) void gemm_al_kernel(
    const float* __restrict__ X, const float* __restrict__ W,
    const float* __restrict__ a_src, const float* __restrict__ a_dst,
    float* __restrict__ H, float* __restrict__ ALs, float* __restrict__ ALd, int nrows) {
    __shared__ float Ws[K * 64];
    for (int i = threadIdx.x; i < K * 64; i += 256) Ws[i] = W[i];
    __syncthreads();

    int wave = threadIdx.x >> 6, lane = threadIdx.x & 63;
    int r0 = blockIdx.x * 16 + wave * 4;
    r0 = __builtin_amdgcn_readfirstlane(r0);  // force wave-uniform -> scalar x loads
    if (r0 >= nrows) return;

    const float* x0 = X + (size_t)r0 * K;
    float acc0 = 0.f, acc1 = 0.f, acc2 = 0.f, acc3 = 0.f;
#pragma unroll 8
    for (int k = 0; k < K; ++k) {
        float w = Ws[k * 64 + lane];
        acc0 = fmaf(x0[k], w, acc0);
        acc1 = fmaf(x0[K + k], w, acc1);
        acc2 = fmaf(x0[2 * K + k], w, acc2);
        acc3 = fmaf(x0[3 * K + k], w, acc3);
    }

    int hh = lane >> 3, cc = lane & 7;
    float as = a_src[hh * 8 + cc];
    float ad = a_dst[hh * 8 + cc];
    float accs[4] = {acc0, acc1, acc2, acc3};
#pragma unroll
    for (int j = 0; j < 4; ++j) {
        int r = r0 + j;
        H[(size_t)r * 64 + lane] = accs[j];
        float ps = accs[j] * as;
        float pd = accs[j] * ad;
#pragma unroll
        for (int off = 1; off < 8; off <<= 1) {
            ps += __shfl_xor(ps, off);
            pd += __shfl_xor(pd, off);
        }
        if (cc == 0) {
            ALs[r * 8 + hh] = ps;
            ALd[r * 8 + hh] = pd;
        }
    }
}

// ---------------- GAT aggregation: one wave per dst node ----------------
// out[d][c] = ELU( (w_self*h[d][c] + sum_in w_e*h[s][c]) / (w_self + sum w_e) + bias[c] )
// w depends only on head (lane>>3); all 8 lanes of a head compute identical wsum.

__global__ __launch_bounds__(256) void agg_kernel(
    const float* __restrict__ H, const float* __restrict__ ALs, const float* __restrict__ ALd,
    const int* __restrict__ rowptr, const int* __restrict__ col,
    const float* __restrict__ bias, float* __restrict__ Out, int n) {
    int wave = threadIdx.x >> 6, lane = threadIdx.x & 63;
    int d = blockIdx.x * 4 + wave;
    if (d >= n) return;
    int hh = lane >> 3;

    float ad = ALd[d * 8 + hh];
    // self loop
    float e = ALs[d * 8 + hh] + ad;
    e = e > 0.f ? e : 0.2f * e;
    float w = __expf(e);
    float acc = w * H[(size_t)d * 64 + lane];
    float wsum = w;

    int beg = rowptr[d], end = rowptr[d + 1];
    for (int i = beg; i < end; ++i) {
        int s = col[i];
        float e2 = ALs[s * 8 + hh] + ad;
        e2 = e2 > 0.f ? e2 : 0.2f * e2;
        float w2 = __expf(e2);
        acc = fmaf(w2, H[(size_t)s * 64 + lane], acc);
        wsum += w2;
    }
    float o = acc / wsum + bias[lane];
    Out[(size_t)d * 64 + lane] = o > 0.f ? o : expm1f(o);
}

// ---------------- global mean pool (batch is sorted) ----------------
// one wave handles 64 consecutive nodes, lane = feature; flush on graph boundary.

__global__ void pool_kernel(const float* __restrict__ H, const int* __restrict__ batch,
                            float* __restrict__ sums, float* __restrict__ cnt, int n) {
    int gw = (int)((blockIdx.x * blockDim.x + threadIdx.x) >> 6);
    int lane = threadIdx.x & 63;
    int n0 = gw * 64;
    if (n0 >= n) return;
    int n1 = min(n0 + 64, n);
    int curb = batch[n0];
    float local = 0.f, c_local = 0.f;
    for (int i = n0; i < n1; ++i) {
        int b = batch[i];
        if (b != curb) {
            atomicAdd(&sums[curb * 64 + lane], local);
            if (lane == 0) atomicAdd(&cnt[curb], c_local);
            local = 0.f;
            c_local = 0.f;
            curb = b;
        }
        local += H[(size_t)i * 64 + lane];
        c_local += 1.f;
    }
    atomicAdd(&sums[curb * 64 + lane], local);
    if (lane == 0) atomicAdd(&cnt[curb], c_local);
}

__global__ void final_kernel(const float* __restrict__ sums, const float* __restrict__ cnt,
                             const float* __restrict__ W, const float* __restrict__ b,
                             float* __restrict__ out) {
    int t = blockIdx.x * blockDim.x + threadIdx.x;
    if (t >= GG * NCLS) return;
    int g = t / NCLS, k = t % NCLS;
    float c = cnt[g];
    if (c < 1.f) c = 1.f;
    float inv = 1.f / c;
    float acc = b[k];
#pragma unroll
    for (int cc = 0; cc < 64; ++cc)
        acc = fmaf(sums[g * 64 + cc] * inv, W[cc * NCLS + k], acc);
    out[t] = acc;
}

// ---------------- launch ----------------

extern "C" void kernel_launch(void* const* d_in, const int* in_sizes, int n_in,
                              void* d_out, int out_size, void* d_ws, size_t ws_size,
                              hipStream_t stream) {
    const float* x    = (const float*)d_in[0];
    const int*   ei   = (const int*)d_in[1];   // [2,E]: src = ei, dst = ei+EE
    const int*   batch = (const int*)d_in[2];
    const float* W1 = (const float*)d_in[3];
    const float* a1s = (const float*)d_in[4];
    const float* a1d = (const float*)d_in[5];
    const float* b1 = (const float*)d_in[6];
    const float* W2 = (const float*)d_in[7];
    const float* a2s = (const float*)d_in[8];
    const float* a2d = (const float*)d_in[9];
    const float* b2 = (const float*)d_in[10];
    const float* W3 = (const float*)d_in[11];
    const float* a3s = (const float*)d_in[12];
    const float* a3d = (const float*)d_in[13];
    const float* b3 = (const float*)d_in[14];
    const float* linW = (const float*)d_in[15];
    const float* linb = (const float*)d_in[16];
    float* out = (float*)d_out;

    char* ws = (char*)d_ws;
    size_t off = 0;
    auto alloc = [&](size_t bytes) -> void* {
        void* p = ws + off;
        off = (off + bytes + 255) & ~(size_t)255;
        return p;
    };
    float* hA     = (float*)alloc((size_t)NN * 64 * 4);   // projected features
    float* hB     = (float*)alloc((size_t)NN * 64 * 4);   // layer outputs
    float* ALs    = (float*)alloc((size_t)NN * 8 * 4);
    float* ALd    = (float*)alloc((size_t)NN * 8 * 4);
    int*   rowptr = (int*)alloc((size_t)(NN + 1) * 4);
    int*   fill   = (int*)alloc((size_t)NN * 4);          // reused: hist counts, then scatter fill
    int*   bsum   = (int*)alloc(512 * 4);
    int*   col    = (int*)alloc((size_t)EE * 4);
    float* sums   = (float*)alloc((size_t)(GG * 64 + GG) * 4);
    float* gcnt   = sums + GG * 64;

    const int NBLK = (NN + 255) / 256;   // 391
    const int EBLK = (EE + 255) / 256;

    // --- CSR by dst (main edges only; self-loops handled inline in agg) ---
    hipMemsetAsync(fill, 0, (size_t)NN * 4, stream);
    hist_kernel<<<EBLK, 256, 0, stream>>>(ei + EE, fill, EE);
    scanA_kernel<<<NBLK, 256, 0, stream>>>(fill, rowptr + 1, bsum, NN);
    scanB_kernel<<<1, 512, 0, stream>>>(bsum, NBLK);
    scanC_kernel<<<NBLK, 256, 0, stream>>>(rowptr, bsum, NN);
    hipMemsetAsync(fill, 0, (size_t)NN * 4, stream);
    scatter_kernel<<<EBLK, 256, 0, stream>>>(ei, ei + EE, rowptr, fill, col, EE);

    // --- 3 GAT layers ---
    const int GB = NN / 16;       // 6250 blocks (16 rows/block)
    const int AB = (NN + 3) / 4;  // 25000 blocks (4 nodes/block)

    gemm_al_kernel<128><<<GB, 256, 0, stream>>>(x, W1, a1s, a1d, hA, ALs, ALd, NN);
    agg_kernel<<<AB, 256, 0, stream>>>(hA, ALs, ALd, rowptr, col, b1, hB, NN);

    gemm_al_kernel<64><<<GB, 256, 0, stream>>>(hB, W2, a2s, a2d, hA, ALs, ALd, NN);
    agg_kernel<<<AB, 256, 0, stream>>>(hA, ALs, ALd, rowptr, col, b2, hB, NN);

    gemm_al_kernel<64><<<GB, 256, 0, stream>>>(hB, W3, a3s, a3d, hA, ALs, ALd, NN);
    agg_kernel<<<AB, 256, 0, stream>>>(hA, ALs, ALd, rowptr, col, b3, hB, NN);

    // --- pool + classifier ---
    hipMemsetAsync(sums, 0, (size_t)(GG * 64 + GG) * 4, stream);
    pool_kernel<<<NBLK, 256, 0, stream>>>(hB, batch, sums, gcnt, NN);
    final_kernel<<<3, 256, 0, stream>>>(sums, gcnt, linW, linb, out);
}

// Round 2
// 685.387 us; speedup vs baseline: 1.3749x; 1.3749x over previous
//
#include <hip/hip_runtime.h>
#include <math.h>

#define NN 100000
#define EE 1600000
#define GG 64
#define NCLS 10

// ---------------- CSR build ----------------

__global__ void hist_kernel(const int* __restrict__ dst, int* __restrict__ cnt, int n) {
    int e = blockIdx.x * 256 + threadIdx.x;
    if (e < n) atomicAdd(&cnt[dst[e]], 1);
}

// inclusive scan per 256-block; writes in-block inclusive to out1[i] (== rowptr+1), block total to bsum
__global__ void scanA_kernel(const int* __restrict__ in, int* __restrict__ out1,
                             int* __restrict__ bsum, int n) {
    __shared__ int s[256];
    int i = blockIdx.x * 256 + threadIdx.x;
    int v = (i < n) ? in[i] : 0;
    s[threadIdx.x] = v;
    __syncthreads();
    for (int off = 1; off < 256; off <<= 1) {
        int t = (threadIdx.x >= (unsigned)off) ? s[threadIdx.x - off] : 0;
        __syncthreads();
        s[threadIdx.x] += t;
        __syncthreads();
    }
    if (i < n) out1[i] = s[threadIdx.x];
    if (threadIdx.x == 255) bsum[blockIdx.x] = s[255];
}

// single-block exclusive scan of block sums (nb <= 512)
__global__ void scanB_kernel(int* __restrict__ bsum, int nb) {
    __shared__ int s[512];
    int v = (threadIdx.x < (unsigned)nb) ? bsum[threadIdx.x] : 0;
    s[threadIdx.x] = v;
    __syncthreads();
    for (int off = 1; off < 512; off <<= 1) {
        int t = (threadIdx.x >= (unsigned)off) ? s[threadIdx.x - off] : 0;
        __syncthreads();
        s[threadIdx.x] += t;
        __syncthreads();
    }
    if (threadIdx.x < (unsigned)nb) bsum[threadIdx.x] = s[threadIdx.x] - v;  // exclusive
}

__global__ void scanC_kernel(int* __restrict__ rowptr, const int* __restrict__ bsum, int n) {
    int i = blockIdx.x * 256 + threadIdx.x;
    if (i < n) rowptr[i + 1] += bsum[blockIdx.x];
    if (i == 0) rowptr[0] = 0;
}

__global__ void scatter_kernel(const int* __restrict__ src, const int* __restrict__ dst,
                               const int* __restrict__ rowptr, int* __restrict__ fill,
                               int* __restrict__ col, int n) {
    int e = blockIdx.x * 256 + threadIdx.x;
    if (e < n) {
        int d = dst[e];
        int p = rowptr[d] + atomicAdd(&fill[d], 1);
        col[p] = src[e];
    }
}

// ---------------- GEMM h = X @ W  (+ per-head attention logits) ----------------
// Block = 256 threads = 4 waves. Each wave: 64 lanes = 64 output cols, 4 rows/thread.
// Block covers 16 rows. W staged in LDS (K*64 floats).

template <int K>
__global__ __launch_bounds__(256) void gemm_al_kernel(
    const float* __restrict__ X, const float* __restrict__ W,
    const float* __restrict__ a_src, const float* __restrict__ a_dst,
    float* __restrict__ H, float* __restrict__ ALs, float* __restrict__ ALd, int nrows) {
    __shared__ float Ws[K * 64];
    for (int i = threadIdx.x; i < K * 64; i += 256) Ws[i] = W[i];
    __syncthreads();

    int wave = threadIdx.x >> 6, lane = threadIdx.x & 63;
    int r0 = blockIdx.x * 16 + wave * 4;
    r0 = __builtin_amdgcn_readfirstlane(r0);  // force wave-uniform -> scalar x loads
    if (r0 >= nrows) return;

    const float* x0 = X + (size_t)r0 * K;
    float acc0 = 0.f, acc1 = 0.f, acc2 = 0.f, acc3 = 0.f;
#pragma unroll 8
    for (int k = 0; k < K; ++k) {
        float w = Ws[k * 64 + lane];
        acc0 = fmaf(x0[k], w, acc0);
        acc1 = fmaf(x0[K + k], w, acc1);
        acc2 = fmaf(x0[2 * K + k], w, acc2);
        acc3 = fmaf(x0[3 * K + k], w, acc3);
    }

    int hh = lane >> 3, cc = lane & 7;
    float as = a_src[hh * 8 + cc];
    float ad = a_dst[hh * 8 + cc];
    float accs[4] = {acc0, acc1, acc2, acc3};
#pragma unroll
    for (int j = 0; j < 4; ++j) {
        int r = r0 + j;
        H[(size_t)r * 64 + lane] = accs[j];
        float ps = accs[j] * as;
        float pd = accs[j] * ad;
#pragma unroll
        for (int off = 1; off < 8; off <<= 1) {
            ps += __shfl_xor(ps, off);
            pd += __shfl_xor(pd, off);
        }
        if (cc == 0) {
            ALs[r * 8 + hh] = ps;
            ALd[r * 8 + hh] = pd;
        }
    }
}

// ---------------- GAT aggregation: one wave per dst node ----------------
// out[d][c] = ELU( (w_self*h[d][c] + sum_in w_e*h[s][c]) / (w_self + sum w_e) + bias[c] )
// MLP strategy: wave-wide coalesced load of up to 64 neighbor ids, __shfl broadcast,
// gathers unrolled x8 so 16 independent loads are in flight per wave.

__global__ __launch_bounds__(256) void agg_kernel(
    const float* __restrict__ H, const float* __restrict__ ALs, const float* __restrict__ ALd,
    const int* __restrict__ rowptr, const int* __restrict__ col,
    const float* __restrict__ bias, float* __restrict__ Out, int n) {
    int wave = threadIdx.x >> 6, lane = threadIdx.x & 63;
    int d = blockIdx.x * 4 + wave;
    if (d >= n) return;
    int hh = lane >> 3;

    float ad = ALd[d * 8 + hh];
    // self loop
    float e = ALs[d * 8 + hh] + ad;
    e = e > 0.f ? e : 0.2f * e;
    float w = __expf(e);
    float acc = w * H[(size_t)d * 64 + lane];
    float wsum = w;

    int beg = rowptr[d], end = rowptr[d + 1];
    for (int base = beg; base < end; base += 64) {
        int m = end - base;
        if (m > 64) m = 64;
        int c = (base + lane < end) ? col[base + lane] : 0;
        int j = 0;
        for (; j + 8 <= m; j += 8) {
            int s0 = __shfl(c, j + 0), s1 = __shfl(c, j + 1);
            int s2 = __shfl(c, j + 2), s3 = __shfl(c, j + 3);
            int s4 = __shfl(c, j + 4), s5 = __shfl(c, j + 5);
            int s6 = __shfl(c, j + 6), s7 = __shfl(c, j + 7);
            // issue all 16 loads before any use
            float h0 = H[(size_t)s0 * 64 + lane], a0 = ALs[s0 * 8 + hh];
            float h1 = H[(size_t)s1 * 64 + lane], a1 = ALs[s1 * 8 + hh];
            float h2 = H[(size_t)s2 * 64 + lane], a2 = ALs[s2 * 8 + hh];
            float h3 = H[(size_t)s3 * 64 + lane], a3 = ALs[s3 * 8 + hh];
            float h4 = H[(size_t)s4 * 64 + lane], a4 = ALs[s4 * 8 + hh];
            float h5 = H[(size_t)s5 * 64 + lane], a5 = ALs[s5 * 8 + hh];
            float h6 = H[(size_t)s6 * 64 + lane], a6 = ALs[s6 * 8 + hh];
            float h7 = H[(size_t)s7 * 64 + lane], a7 = ALs[s7 * 8 + hh];
            float e0 = a0 + ad; e0 = e0 > 0.f ? e0 : 0.2f * e0; float w0 = __expf(e0);
            float e1 = a1 + ad; e1 = e1 > 0.f ? e1 : 0.2f * e1; float w1 = __expf(e1);
            float e2 = a2 + ad; e2 = e2 > 0.f ? e2 : 0.2f * e2; float w2 = __expf(e2);
            float e3 = a3 + ad; e3 = e3 > 0.f ? e3 : 0.2f * e3; float w3 = __expf(e3);
            float e4 = a4 + ad; e4 = e4 > 0.f ? e4 : 0.2f * e4; float w4 = __expf(e4);
            float e5 = a5 + ad; e5 = e5 > 0.f ? e5 : 0.2f * e5; float w5 = __expf(e5);
            float e6 = a6 + ad; e6 = e6 > 0.f ? e6 : 0.2f * e6; float w6 = __expf(e6);
            float e7 = a7 + ad; e7 = e7 > 0.f ? e7 : 0.2f * e7; float w7 = __expf(e7);
            acc = fmaf(w0, h0, acc); wsum += w0;
            acc = fmaf(w1, h1, acc); wsum += w1;
            acc = fmaf(w2, h2, acc); wsum += w2;
            acc = fmaf(w3, h3, acc); wsum += w3;
            acc = fmaf(w4, h4, acc); wsum += w4;
            acc = fmaf(w5, h5, acc); wsum += w5;
            acc = fmaf(w6, h6, acc); wsum += w6;
            acc = fmaf(w7, h7, acc); wsum += w7;
        }
        for (; j < m; ++j) {
            int s = __shfl(c, j);
            float hx = H[(size_t)s * 64 + lane];
            float ax = ALs[s * 8 + hh];
            float e2 = ax + ad;
            e2 = e2 > 0.f ? e2 : 0.2f * e2;
            float w2 = __expf(e2);
            acc = fmaf(w2, hx, acc);
            wsum += w2;
        }
    }
    float o = acc / wsum + bias[lane];
    Out[(size_t)d * 64 + lane] = o > 0.f ? o : expm1f(o);
}

// ---------------- global mean pool (batch is sorted) ----------------
// one wave handles 64 consecutive nodes, lane = feature; flush on graph boundary.

__global__ void pool_kernel(const float* __restrict__ H, const int* __restrict__ batch,
                            float* __restrict__ sums, float* __restrict__ cnt, int n) {
    int gw = (int)((blockIdx.x * blockDim.x + threadIdx.x) >> 6);
    int lane = threadIdx.x & 63;
    int n0 = gw * 64;
    if (n0 >= n) return;
    int n1 = min(n0 + 64, n);
    int curb = batch[n0];
    float local = 0.f, c_local = 0.f;
    for (int i = n0; i < n1; ++i) {
        int b = batch[i];
        if (b != curb) {
            atomicAdd(&sums[curb * 64 + lane], local);
            if (lane == 0) atomicAdd(&cnt[curb], c_local);
            local = 0.f;
            c_local = 0.f;
            curb = b;
        }
        local += H[(size_t)i * 64 + lane];
        c_local += 1.f;
    }
    atomicAdd(&sums[curb * 64 + lane], local);
    if (lane == 0) atomicAdd(&cnt[curb], c_local);
}

__global__ void final_kernel(const float* __restrict__ sums, const float* __restrict__ cnt,
                             const float* __restrict__ W, const float* __restrict__ b,
                             float* __restrict__ out) {
    int t = blockIdx.x * blockDim.x + threadIdx.x;
    if (t >= GG * NCLS) return;
    int g = t / NCLS, k = t % NCLS;
    float c = cnt[g];
    if (c < 1.f) c = 1.f;
    float inv = 1.f / c;
    float acc = b[k];
#pragma unroll
    for (int cc = 0; cc < 64; ++cc)
        acc = fmaf(sums[g * 64 + cc] * inv, W[cc * NCLS + k], acc);
    out[t] = acc;
}

// ---------------- launch ----------------

extern "C" void kernel_launch(void* const* d_in, const int* in_sizes, int n_in,
                              void* d_out, int out_size, void* d_ws, size_t ws_size,
                              hipStream_t stream) {
    const float* x    = (const float*)d_in[0];
    const int*   ei   = (const int*)d_in[1];   // [2,E]: src = ei, dst = ei+EE
    const int*   batch = (const int*)d_in[2];
    const float* W1 = (const float*)d_in[3];
    const float* a1s = (const float*)d_in[4];
    const float* a1d = (const float*)d_in[5];
    const float* b1 = (const float*)d_in[6];
    const float* W2 = (const float*)d_in[7];
    const float* a2s = (const float*)d_in[8];
    const float* a2d = (const float*)d_in[9];
    const float* b2 = (const float*)d_in[10];
    const float* W3 = (const float*)d_in[11];
    const float* a3s = (const float*)d_in[12];
    const float* a3d = (const float*)d_in[13];
    const float* b3 = (const float*)d_in[14];
    const float* linW = (const float*)d_in[15];
    const float* linb = (const float*)d_in[16];
    float* out = (float*)d_out;

    char* ws = (char*)d_ws;
    size_t off = 0;
    auto alloc = [&](size_t bytes) -> void* {
        void* p = ws + off;
        off = (off + bytes + 255) & ~(size_t)255;
        return p;
    };
    float* hA     = (float*)alloc((size_t)NN * 64 * 4);   // projected features
    float* hB     = (float*)alloc((size_t)NN * 64 * 4);   // layer outputs
    float* ALs    = (float*)alloc((size_t)NN * 8 * 4);
    float* ALd    = (float*)alloc((size_t)NN * 8 * 4);
    int*   rowptr = (int*)alloc((size_t)(NN + 1) * 4);
    int*   fill   = (int*)alloc((size_t)NN * 4);          // reused: hist counts, then scatter fill
    int*   bsum   = (int*)alloc(512 * 4);
    int*   col    = (int*)alloc((size_t)EE * 4);
    float* sums   = (float*)alloc((size_t)(GG * 64 + GG) * 4);
    float* gcnt   = sums + GG * 64;

    const int NBLK = (NN + 255) / 256;   // 391
    const int EBLK = (EE + 255) / 256;

    // --- CSR by dst (main edges only; self-loops handled inline in agg) ---
    hipMemsetAsync(fill, 0, (size_t)NN * 4, stream);
    hist_kernel<<<EBLK, 256, 0, stream>>>(ei + EE, fill, EE);
    scanA_kernel<<<NBLK, 256, 0, stream>>>(fill, rowptr + 1, bsum, NN);
    scanB_kernel<<<1, 512, 0, stream>>>(bsum, NBLK);
    scanC_kernel<<<NBLK, 256, 0, stream>>>(rowptr, bsum, NN);
    hipMemsetAsync(fill, 0, (size_t)NN * 4, stream);
    scatter_kernel<<<EBLK, 256, 0, stream>>>(ei, ei + EE, rowptr, fill, col, EE);

    // --- 3 GAT layers ---
    const int GB = NN / 16;       // 6250 blocks (16 rows/block)
    const int AB = (NN + 3) / 4;  // 25000 blocks (4 nodes/block)

    gemm_al_kernel<128><<<GB, 256, 0, stream>>>(x, W1, a1s, a1d, hA, ALs, ALd, NN);
    agg_kernel<<<AB, 256, 0, stream>>>(hA, ALs, ALd, rowptr, col, b1, hB, NN);

    gemm_al_kernel<64><<<GB, 256, 0, stream>>>(hB, W2, a2s, a2d, hA, ALs, ALd, NN);
    agg_kernel<<<AB, 256, 0, stream>>>(hA, ALs, ALd, rowptr, col, b2, hB, NN);

    gemm_al_kernel<64><<<GB, 256, 0, stream>>>(hB, W3, a3s, a3d, hA, ALs, ALd, NN);
    agg_kernel<<<AB, 256, 0, stream>>>(hA, ALs, ALd, rowptr, col, b3, hB, NN);

    // --- pool + classifier ---
    hipMemsetAsync(sums, 0, (size_t)(GG * 64 + GG) * 4, stream);
    pool_kernel<<<NBLK, 256, 0, stream>>>(hB, batch, sums, gcnt, NN);
    final_kernel<<<3, 256, 0, stream>>>(sums, gcnt, linW, linb, out);
}

// Round 3
// 560.980 us; speedup vs baseline: 1.6798x; 1.2218x over previous
//
#include <hip/hip_runtime.h>
#include <math.h>

#define NN 100000
#define EE 1600000
#define GG 64
#define NCLS 10

#define BSH 9                 // bucket = dst >> 9 (512 nodes per bucket)
#define NB 196                // ceil(NN / 512)
#define EPB 4096              // edges per block in bscatter
#define CAP 10240             // bsort LDS staging capacity (ints)

// ---------------- CSR build: two-level counting sort ----------------

// K1: coarse histogram of 256 buckets
__global__ __launch_bounds__(256) void bhist_kernel(const int* __restrict__ dst,
                                                    int* __restrict__ bcnt, int n) {
    __shared__ int h[256];
    int tid = threadIdx.x;
    h[tid] = 0;
    __syncthreads();
    int e0 = blockIdx.x * EPB;
    int e1 = min(e0 + EPB, n);
    for (int e = e0 + tid; e < e1; e += 256) atomicAdd(&h[dst[e] >> BSH], 1);
    __syncthreads();
    if (h[tid]) atomicAdd(&bcnt[tid], h[tid]);
}

// K2: exclusive scan of 256 bucket counts -> bbase[0..256]
__global__ void bscan_kernel(const int* __restrict__ bcnt, int* __restrict__ bbase) {
    __shared__ int s[256];
    int tid = threadIdx.x;
    int v = bcnt[tid];
    s[tid] = v;
    __syncthreads();
    for (int off = 1; off < 256; off <<= 1) {
        int t = (tid >= off) ? s[tid - off] : 0;
        __syncthreads();
        s[tid] += t;
        __syncthreads();
    }
    bbase[tid + 1] = s[tid];
    if (tid == 0) bbase[0] = 0;
}

// K3: scatter edges into bucketed arrays, LDS-staged so global writes are dense runs
__global__ __launch_bounds__(256) void bscatter_kernel(
    const int* __restrict__ src, const int* __restrict__ dst,
    int* __restrict__ bfill, const int* __restrict__ bbase,
    int* __restrict__ bsrc, int* __restrict__ bdst, int n) {
    __shared__ int hist[256], lbase[256], goff[256], cnt2[256], sc[256];
    __shared__ int ls[EPB], ld2[EPB];
    __shared__ unsigned char bkt[EPB];
    int tid = threadIdx.x;
    int e0 = blockIdx.x * EPB;
    int e1 = min(e0 + EPB, n);

    hist[tid] = 0;
    cnt2[tid] = 0;
    __syncthreads();
    // phase 1: count per bucket
    for (int e = e0 + tid; e < e1; e += 256) atomicAdd(&hist[dst[e] >> BSH], 1);
    __syncthreads();
    // phase 2: local exclusive scan + reserve global chunk per bucket
    sc[tid] = hist[tid];
    __syncthreads();
    for (int off = 1; off < 256; off <<= 1) {
        int t = (tid >= off) ? sc[tid - off] : 0;
        __syncthreads();
        sc[tid] += t;
        __syncthreads();
    }
    lbase[tid] = sc[tid] - hist[tid];
    goff[tid] = hist[tid] > 0 ? atomicAdd(&bfill[tid], hist[tid]) : 0;
    __syncthreads();
    // phase 3: rank within block, stage into LDS in bucket order
    for (int e = e0 + tid; e < e1; e += 256) {
        int s = src[e], d = dst[e];
        int b = d >> BSH;
        int r = atomicAdd(&cnt2[b], 1);
        int slot = lbase[b] + r;
        ls[slot] = s;
        ld2[slot] = d;
        bkt[slot] = (unsigned char)b;
    }
    __syncthreads();
    // phase 4: copy out — consecutive slots in same bucket -> consecutive global addrs
    int m = e1 - e0;
    for (int i = tid; i < m; i += 256) {
        int b = bkt[i];
        int g = bbase[b] + goff[b] + (i - lbase[b]);
        bsrc[g] = ls[i];
        bdst[g] = ld2[i];
    }
}

// K4: per-bucket counting sort -> rowptr + col (one block of 512 threads per bucket)
__global__ __launch_bounds__(512) void bsort_kernel(
    const int* __restrict__ bsrc, const int* __restrict__ bdst,
    const int* __restrict__ bbase, int* __restrict__ rowptr, int* __restrict__ col) {
    __shared__ int cnt[512], cnt2[512], sc[512];
    __shared__ int stage[CAP];
    int b = blockIdx.x;
    int tid = threadIdx.x;
    int ebeg = bbase[b], eend = bbase[b + 1];
    int n0 = b << BSH;
    int nn = min(512, NN - n0);

    cnt[tid] = 0;
    cnt2[tid] = 0;
    __syncthreads();
    for (int e = ebeg + tid; e < eend; e += 512) atomicAdd(&cnt[bdst[e] - n0], 1);
    __syncthreads();
    sc[tid] = cnt[tid];
    __syncthreads();
    for (int off = 1; off < 512; off <<= 1) {
        int t = (tid >= off) ? sc[tid - off] : 0;
        __syncthreads();
        sc[tid] += t;
        __syncthreads();
    }
    int excl = sc[tid] - cnt[tid];
    sc[tid] = excl;  // reuse sc as exclusive offsets
    if (tid < nn) rowptr[n0 + tid] = ebeg + excl;
    if (b == NB - 1 && tid == 0) rowptr[NN] = eend;
    __syncthreads();
    int sz = eend - ebeg;
    bool fits = sz <= CAP;
    for (int e = ebeg + tid; e < eend; e += 512) {
        int d = bdst[e] - n0;
        int r = atomicAdd(&cnt2[d], 1);
        int p = sc[d] + r;
        if (fits) stage[p] = bsrc[e];
        else col[ebeg + p] = bsrc[e];
    }
    __syncthreads();
    if (fits)
        for (int i = tid; i < sz; i += 512) col[ebeg + i] = stage[i];
}

// ---------------- GEMM h = X @ W  (+ per-head attention logits) ----------------

template <int K>
__global__ __launch_bounds__(256) void gemm_al_kernel(
    const float* __restrict__ X, const float* __restrict__ W,
    const float* __restrict__ a_src, const float* __restrict__ a_dst,
    float* __restrict__ H, float* __restrict__ ALs, float* __restrict__ ALd, int nrows) {
    __shared__ float Ws[K * 64];
    for (int i = threadIdx.x; i < K * 64; i += 256) Ws[i] = W[i];
    __syncthreads();

    int wave = threadIdx.x >> 6, lane = threadIdx.x & 63;
    int r0 = blockIdx.x * 16 + wave * 4;
    r0 = __builtin_amdgcn_readfirstlane(r0);  // force wave-uniform -> scalar x loads
    if (r0 >= nrows) return;

    const float* x0 = X + (size_t)r0 * K;
    float acc0 = 0.f, acc1 = 0.f, acc2 = 0.f, acc3 = 0.f;
#pragma unroll 8
    for (int k = 0; k < K; ++k) {
        float w = Ws[k * 64 + lane];
        acc0 = fmaf(x0[k], w, acc0);
        acc1 = fmaf(x0[K + k], w, acc1);
        acc2 = fmaf(x0[2 * K + k], w, acc2);
        acc3 = fmaf(x0[3 * K + k], w, acc3);
    }

    int hh = lane >> 3, cc = lane & 7;
    float as = a_src[hh * 8 + cc];
    float ad = a_dst[hh * 8 + cc];
    float accs[4] = {acc0, acc1, acc2, acc3};
#pragma unroll
    for (int j = 0; j < 4; ++j) {
        int r = r0 + j;
        H[(size_t)r * 64 + lane] = accs[j];
        float ps = accs[j] * as;
        float pd = accs[j] * ad;
#pragma unroll
        for (int off = 1; off < 8; off <<= 1) {
            ps += __shfl_xor(ps, off);
            pd += __shfl_xor(pd, off);
        }
        if (cc == 0) {
            ALs[r * 8 + hh] = ps;
            ALd[r * 8 + hh] = pd;
        }
    }
}

// ---------------- GAT aggregation: one wave per dst node ----------------

__global__ __launch_bounds__(256) void agg_kernel(
    const float* __restrict__ H, const float* __restrict__ ALs, const float* __restrict__ ALd,
    const int* __restrict__ rowptr, const int* __restrict__ col,
    const float* __restrict__ bias, float* __restrict__ Out, int n) {
    int wave = threadIdx.x >> 6, lane = threadIdx.x & 63;
    int d = blockIdx.x * 4 + wave;
    if (d >= n) return;
    int hh = lane >> 3;

    float ad = ALd[d * 8 + hh];
    // self loop
    float e = ALs[d * 8 + hh] + ad;
    e = e > 0.f ? e : 0.2f * e;
    float w = __expf(e);
    float acc = w * H[(size_t)d * 64 + lane];
    float wsum = w;

    int beg = rowptr[d], end = rowptr[d + 1];
    for (int base = beg; base < end; base += 64) {
        int m = end - base;
        if (m > 64) m = 64;
        int c = (base + lane < end) ? col[base + lane] : 0;
        int j = 0;
        for (; j + 8 <= m; j += 8) {
            int s0 = __shfl(c, j + 0), s1 = __shfl(c, j + 1);
            int s2 = __shfl(c, j + 2), s3 = __shfl(c, j + 3);
            int s4 = __shfl(c, j + 4), s5 = __shfl(c, j + 5);
            int s6 = __shfl(c, j + 6), s7 = __shfl(c, j + 7);
            float h0 = H[(size_t)s0 * 64 + lane], a0 = ALs[s0 * 8 + hh];
            float h1 = H[(size_t)s1 * 64 + lane], a1 = ALs[s1 * 8 + hh];
            float h2 = H[(size_t)s2 * 64 + lane], a2 = ALs[s2 * 8 + hh];
            float h3 = H[(size_t)s3 * 64 + lane], a3 = ALs[s3 * 8 + hh];
            float h4 = H[(size_t)s4 * 64 + lane], a4 = ALs[s4 * 8 + hh];
            float h5 = H[(size_t)s5 * 64 + lane], a5 = ALs[s5 * 8 + hh];
            float h6 = H[(size_t)s6 * 64 + lane], a6 = ALs[s6 * 8 + hh];
            float h7 = H[(size_t)s7 * 64 + lane], a7 = ALs[s7 * 8 + hh];
            float e0 = a0 + ad; e0 = e0 > 0.f ? e0 : 0.2f * e0; float w0 = __expf(e0);
            float e1 = a1 + ad; e1 = e1 > 0.f ? e1 : 0.2f * e1; float w1 = __expf(e1);
            float e2 = a2 + ad; e2 = e2 > 0.f ? e2 : 0.2f * e2; float w2 = __expf(e2);
            float e3 = a3 + ad; e3 = e3 > 0.f ? e3 : 0.2f * e3; float w3 = __expf(e3);
            float e4 = a4 + ad; e4 = e4 > 0.f ? e4 : 0.2f * e4; float w4 = __expf(e4);
            float e5 = a5 + ad; e5 = e5 > 0.f ? e5 : 0.2f * e5; float w5 = __expf(e5);
            float e6 = a6 + ad; e6 = e6 > 0.f ? e6 : 0.2f * e6; float w6 = __expf(e6);
            float e7 = a7 + ad; e7 = e7 > 0.f ? e7 : 0.2f * e7; float w7 = __expf(e7);
            acc = fmaf(w0, h0, acc); wsum += w0;
            acc = fmaf(w1, h1, acc); wsum += w1;
            acc = fmaf(w2, h2, acc); wsum += w2;
            acc = fmaf(w3, h3, acc); wsum += w3;
            acc = fmaf(w4, h4, acc); wsum += w4;
            acc = fmaf(w5, h5, acc); wsum += w5;
            acc = fmaf(w6, h6, acc); wsum += w6;
            acc = fmaf(w7, h7, acc); wsum += w7;
        }
        for (; j < m; ++j) {
            int s = __shfl(c, j);
            float hx = H[(size_t)s * 64 + lane];
            float ax = ALs[s * 8 + hh];
            float e2 = ax + ad;
            e2 = e2 > 0.f ? e2 : 0.2f * e2;
            float w2 = __expf(e2);
            acc = fmaf(w2, hx, acc);
            wsum += w2;
        }
    }
    float o = acc / wsum + bias[lane];
    Out[(size_t)d * 64 + lane] = o > 0.f ? o : expm1f(o);
}

// ---------------- global mean pool (batch is sorted) ----------------

__global__ void pool_kernel(const float* __restrict__ H, const int* __restrict__ batch,
                            float* __restrict__ sums, float* __restrict__ cnt, int n) {
    int gw = (int)((blockIdx.x * blockDim.x + threadIdx.x) >> 6);
    int lane = threadIdx.x & 63;
    int n0 = gw * 64;
    if (n0 >= n) return;
    int n1 = min(n0 + 64, n);
    int curb = batch[n0];
    float local = 0.f, c_local = 0.f;
    for (int i = n0; i < n1; ++i) {
        int b = batch[i];
        if (b != curb) {
            atomicAdd(&sums[curb * 64 + lane], local);
            if (lane == 0) atomicAdd(&cnt[curb], c_local);
            local = 0.f;
            c_local = 0.f;
            curb = b;
        }
        local += H[(size_t)i * 64 + lane];
        c_local += 1.f;
    }
    atomicAdd(&sums[curb * 64 + lane], local);
    if (lane == 0) atomicAdd(&cnt[curb], c_local);
}

__global__ void final_kernel(const float* __restrict__ sums, const float* __restrict__ cnt,
                             const float* __restrict__ W, const float* __restrict__ b,
                             float* __restrict__ out) {
    int t = blockIdx.x * blockDim.x + threadIdx.x;
    if (t >= GG * NCLS) return;
    int g = t / NCLS, k = t % NCLS;
    float c = cnt[g];
    if (c < 1.f) c = 1.f;
    float inv = 1.f / c;
    float acc = b[k];
#pragma unroll
    for (int cc = 0; cc < 64; ++cc)
        acc = fmaf(sums[g * 64 + cc] * inv, W[cc * NCLS + k], acc);
    out[t] = acc;
}

// ---------------- launch ----------------

extern "C" void kernel_launch(void* const* d_in, const int* in_sizes, int n_in,
                              void* d_out, int out_size, void* d_ws, size_t ws_size,
                              hipStream_t stream) {
    const float* x    = (const float*)d_in[0];
    const int*   ei   = (const int*)d_in[1];   // [2,E]: src = ei, dst = ei+EE
    const int*   batch = (const int*)d_in[2];
    const float* W1 = (const float*)d_in[3];
    const float* a1s = (const float*)d_in[4];
    const float* a1d = (const float*)d_in[5];
    const float* b1 = (const float*)d_in[6];
    const float* W2 = (const float*)d_in[7];
    const float* a2s = (const float*)d_in[8];
    const float* a2d = (const float*)d_in[9];
    const float* b2 = (const float*)d_in[10];
    const float* W3 = (const float*)d_in[11];
    const float* a3s = (const float*)d_in[12];
    const float* a3d = (const float*)d_in[13];
    const float* b3 = (const float*)d_in[14];
    const float* linW = (const float*)d_in[15];
    const float* linb = (const float*)d_in[16];
    float* out = (float*)d_out;

    char* ws = (char*)d_ws;
    size_t off = 0;
    auto alloc = [&](size_t bytes) -> void* {
        void* p = ws + off;
        off = (off + bytes + 255) & ~(size_t)255;
        return p;
    };
    float* hA     = (float*)alloc((size_t)NN * 64 * 4);   // projected features
    float* hB     = (float*)alloc((size_t)NN * 64 * 4);   // layer outputs
    float* ALs    = (float*)alloc((size_t)NN * 8 * 4);
    float* ALd    = (float*)alloc((size_t)NN * 8 * 4);
    int*   rowptr = (int*)alloc((size_t)(NN + 1) * 4);
    int*   bcnt   = (int*)alloc(256 * 4);
    int*   bfill  = (int*)alloc(256 * 4);
    int*   bbase  = (int*)alloc(257 * 4);
    int*   bsrc   = (int*)alloc((size_t)EE * 4);
    int*   bdst   = (int*)alloc((size_t)EE * 4);
    int*   col    = (int*)alloc((size_t)EE * 4);
    float* sums   = (float*)alloc((size_t)(GG * 64 + GG) * 4);
    float* gcnt   = sums + GG * 64;

    const int NBLK = (NN + 255) / 256;   // 391
    const int EB4 = (EE + EPB - 1) / EPB; // 391

    // --- CSR by dst via two-level counting sort (self-loops handled inline in agg) ---
    hipMemsetAsync(bcnt, 0, 512 * 4, stream);  // bcnt + bfill (contiguous after align? no — separate)
    hipMemsetAsync(bfill, 0, 256 * 4, stream);
    bhist_kernel<<<EB4, 256, 0, stream>>>(ei + EE, bcnt, EE);
    bscan_kernel<<<1, 256, 0, stream>>>(bcnt, bbase);
    bscatter_kernel<<<EB4, 256, 0, stream>>>(ei, ei + EE, bfill, bbase, bsrc, bdst, EE);
    bsort_kernel<<<NB, 512, 0, stream>>>(bsrc, bdst, bbase, rowptr, col);

    // --- 3 GAT layers ---
    const int GB = NN / 16;       // 6250 blocks (16 rows/block)
    const int AB = (NN + 3) / 4;  // 25000 blocks (4 nodes/block)

    gemm_al_kernel<128><<<GB, 256, 0, stream>>>(x, W1, a1s, a1d, hA, ALs, ALd, NN);
    agg_kernel<<<AB, 256, 0, stream>>>(hA, ALs, ALd, rowptr, col, b1, hB, NN);

    gemm_al_kernel<64><<<GB, 256, 0, stream>>>(hB, W2, a2s, a2d, hA, ALs, ALd, NN);
    agg_kernel<<<AB, 256, 0, stream>>>(hA, ALs, ALd, rowptr, col, b2, hB, NN);

    gemm_al_kernel<64><<<GB, 256, 0, stream>>>(hB, W3, a3s, a3d, hA, ALs, ALd, NN);
    agg_kernel<<<AB, 256, 0, stream>>>(hA, ALs, ALd, rowptr, col, b3, hB, NN);

    // --- pool + classifier ---
    hipMemsetAsync(sums, 0, (size_t)(GG * 64 + GG) * 4, stream);
    pool_kernel<<<NBLK, 256, 0, stream>>>(hB, batch, sums, gcnt, NN);
    final_kernel<<<3, 256, 0, stream>>>(sums, gcnt, linW, linb, out);
}

// Round 4
// 550.231 us; speedup vs baseline: 1.7126x; 1.0195x over previous
//
#include <hip/hip_runtime.h>
#include <math.h>

#define NN 100000
#define EE 1600000
#define GG 64
#define NCLS 10

#define BSH 9                 // bucket = dst >> 9 (512 nodes per bucket)
#define NB 196                // ceil(NN / 512)
#define EPB 4096              // edges per block in bscatter
#define CAP 10240             // bsort LDS staging capacity (ints)

// ---------------- CSR build: two-level counting sort ----------------

__global__ __launch_bounds__(256) void bhist_kernel(const int* __restrict__ dst,
                                                    int* __restrict__ bcnt, int n) {
    __shared__ int h[256];
    int tid = threadIdx.x;
    h[tid] = 0;
    __syncthreads();
    int e0 = blockIdx.x * EPB;
    int e1 = min(e0 + EPB, n);
    for (int e = e0 + tid; e < e1; e += 256) atomicAdd(&h[dst[e] >> BSH], 1);
    __syncthreads();
    if (h[tid]) atomicAdd(&bcnt[tid], h[tid]);
}

__global__ void bscan_kernel(const int* __restrict__ bcnt, int* __restrict__ bbase) {
    __shared__ int s[256];
    int tid = threadIdx.x;
    int v = bcnt[tid];
    s[tid] = v;
    __syncthreads();
    for (int off = 1; off < 256; off <<= 1) {
        int t = (tid >= off) ? s[tid - off] : 0;
        __syncthreads();
        s[tid] += t;
        __syncthreads();
    }
    bbase[tid + 1] = s[tid];
    if (tid == 0) bbase[0] = 0;
}

__global__ __launch_bounds__(256) void bscatter_kernel(
    const int* __restrict__ src, const int* __restrict__ dst,
    int* __restrict__ bfill, const int* __restrict__ bbase,
    int* __restrict__ bsrc, int* __restrict__ bdst, int n) {
    __shared__ int hist[256], lbase[256], goff[256], cnt2[256], sc[256];
    __shared__ int ls[EPB], ld2[EPB];
    __shared__ unsigned char bkt[EPB];
    int tid = threadIdx.x;
    int e0 = blockIdx.x * EPB;
    int e1 = min(e0 + EPB, n);

    hist[tid] = 0;
    cnt2[tid] = 0;
    __syncthreads();
    for (int e = e0 + tid; e < e1; e += 256) atomicAdd(&hist[dst[e] >> BSH], 1);
    __syncthreads();
    sc[tid] = hist[tid];
    __syncthreads();
    for (int off = 1; off < 256; off <<= 1) {
        int t = (tid >= off) ? sc[tid - off] : 0;
        __syncthreads();
        sc[tid] += t;
        __syncthreads();
    }
    lbase[tid] = sc[tid] - hist[tid];
    goff[tid] = hist[tid] > 0 ? atomicAdd(&bfill[tid], hist[tid]) : 0;
    __syncthreads();
    for (int e = e0 + tid; e < e1; e += 256) {
        int s = src[e], d = dst[e];
        int b = d >> BSH;
        int r = atomicAdd(&cnt2[b], 1);
        int slot = lbase[b] + r;
        ls[slot] = s;
        ld2[slot] = d;
        bkt[slot] = (unsigned char)b;
    }
    __syncthreads();
    int m = e1 - e0;
    for (int i = tid; i < m; i += 256) {
        int b = bkt[i];
        int g = bbase[b] + goff[b] + (i - lbase[b]);
        bsrc[g] = ls[i];
        bdst[g] = ld2[i];
    }
}

__global__ __launch_bounds__(512) void bsort_kernel(
    const int* __restrict__ bsrc, const int* __restrict__ bdst,
    const int* __restrict__ bbase, int* __restrict__ rowptr, int* __restrict__ col) {
    __shared__ int cnt[512], cnt2[512], sc[512];
    __shared__ int stage[CAP];
    int b = blockIdx.x;
    int tid = threadIdx.x;
    int ebeg = bbase[b], eend = bbase[b + 1];
    int n0 = b << BSH;
    int nn = min(512, NN - n0);

    cnt[tid] = 0;
    cnt2[tid] = 0;
    __syncthreads();
    for (int e = ebeg + tid; e < eend; e += 512) atomicAdd(&cnt[bdst[e] - n0], 1);
    __syncthreads();
    sc[tid] = cnt[tid];
    __syncthreads();
    for (int off = 1; off < 512; off <<= 1) {
        int t = (tid >= off) ? sc[tid - off] : 0;
        __syncthreads();
        sc[tid] += t;
        __syncthreads();
    }
    int excl = sc[tid] - cnt[tid];
    sc[tid] = excl;
    if (tid < nn) rowptr[n0 + tid] = ebeg + excl;
    if (b == NB - 1 && tid == 0) rowptr[NN] = eend;
    __syncthreads();
    int sz = eend - ebeg;
    bool fits = sz <= CAP;
    for (int e = ebeg + tid; e < eend; e += 512) {
        int d = bdst[e] - n0;
        int r = atomicAdd(&cnt2[d], 1);
        int p = sc[d] + r;
        if (fits) stage[p] = bsrc[e];
        else col[ebeg + p] = bsrc[e];
    }
    __syncthreads();
    if (fits)
        for (int i = tid; i < sz; i += 512) col[ebeg + i] = stage[i];
}

// ---------------- GEMM h = X @ W  (+ per-head attention logits) ----------------

template <int K>
__global__ __launch_bounds__(256) void gemm_al_kernel(
    const float* __restrict__ X, const float* __restrict__ W,
    const float* __restrict__ a_src, const float* __restrict__ a_dst,
    float* __restrict__ H, float* __restrict__ ALs, float* __restrict__ ALd, int nrows) {
    __shared__ float Ws[K * 64];
    for (int i = threadIdx.x; i < K * 64; i += 256) Ws[i] = W[i];
    __syncthreads();

    int wave = threadIdx.x >> 6, lane = threadIdx.x & 63;
    int r0 = blockIdx.x * 16 + wave * 4;
    r0 = __builtin_amdgcn_readfirstlane(r0);
    if (r0 >= nrows) return;

    const float* x0 = X + (size_t)r0 * K;
    float acc0 = 0.f, acc1 = 0.f, acc2 = 0.f, acc3 = 0.f;
#pragma unroll 8
    for (int k = 0; k < K; ++k) {
        float w = Ws[k * 64 + lane];
        acc0 = fmaf(x0[k], w, acc0);
        acc1 = fmaf(x0[K + k], w, acc1);
        acc2 = fmaf(x0[2 * K + k], w, acc2);
        acc3 = fmaf(x0[3 * K + k], w, acc3);
    }

    int hh = lane >> 3, cc = lane & 7;
    float as = a_src[hh * 8 + cc];
    float ad = a_dst[hh * 8 + cc];
    float accs[4] = {acc0, acc1, acc2, acc3};
#pragma unroll
    for (int j = 0; j < 4; ++j) {
        int r = r0 + j;
        H[(size_t)r * 64 + lane] = accs[j];
        float ps = accs[j] * as;
        float pd = accs[j] * ad;
#pragma unroll
        for (int off = 1; off < 8; off <<= 1) {
            ps += __shfl_xor(ps, off);
            pd += __shfl_xor(pd, off);
        }
        if (cc == 0) {
            ALs[r * 8 + hh] = ps;
            ALd[r * 8 + hh] = pd;
        }
    }
}

// ---------------- GAT aggregation: one wave per dst node, float4 gathers ----------------
// Wave = 4 quarter-waves of 16 lanes. Lane ql in a quarter holds features 4ql..4ql+3
// (never crosses a head boundary -> head = ql>>1). Quarter q consumes edges j = 4k+q.
// One global_load_dwordx4 instruction fetches FOUR edges' 256B H rows (64 lanes x 16B).
// Loads are unpredicated: index clamped to m-1, contribution killed via w=0.
// Final 2-round shfl_xor(16,32) merges the four per-quarter partials.

__global__ __launch_bounds__(256) void agg_kernel(
    const float* __restrict__ H, const float* __restrict__ ALs, const float* __restrict__ ALd,
    const int* __restrict__ rowptr, const int* __restrict__ col,
    const float* __restrict__ bias, float* __restrict__ Out, int n) {
    int wave = threadIdx.x >> 6, lane = threadIdx.x & 63;
    int d = blockIdx.x * 4 + wave;
    if (d >= n) return;
    int q = lane >> 4, ql = lane & 15;
    int hh = ql >> 1;
    const float4* __restrict__ H4 = (const float4*)H;

    float ad = ALd[d * 8 + hh];
    float4 acc = make_float4(0.f, 0.f, 0.f, 0.f);
    float wsum = 0.f;
    if (q == 0) {  // self loop counted once
        float e = ALs[d * 8 + hh] + ad;
        e = e > 0.f ? e : 0.2f * e;
        float w = __expf(e);
        float4 hv = H4[d * 16 + ql];
        acc.x = w * hv.x; acc.y = w * hv.y; acc.z = w * hv.z; acc.w = w * hv.w;
        wsum = w;
    }

    int beg = rowptr[d], end = rowptr[d + 1];
    for (int base = beg; base < end; base += 64) {
        int m = end - base;
        if (m > 64) m = 64;
        int c = (base + lane < end) ? col[base + lane] : 0;
        int steps = (m + 3) >> 2;   // max steps over quarters
        int k = 0;
        for (; k + 4 <= steps; k += 4) {
            int j0 = 4 * k + q, j1 = j0 + 4, j2 = j0 + 8, j3 = j0 + 12;
            int i0 = min(j0, m - 1), i1 = min(j1, m - 1);
            int i2 = min(j2, m - 1), i3 = min(j3, m - 1);
            int s0 = __shfl(c, i0), s1 = __shfl(c, i1);
            int s2 = __shfl(c, i2), s3 = __shfl(c, i3);
            float4 h0 = H4[s0 * 16 + ql]; float a0 = ALs[s0 * 8 + hh];
            float4 h1 = H4[s1 * 16 + ql]; float a1 = ALs[s1 * 8 + hh];
            float4 h2 = H4[s2 * 16 + ql]; float a2 = ALs[s2 * 8 + hh];
            float4 h3 = H4[s3 * 16 + ql]; float a3 = ALs[s3 * 8 + hh];
            float e0 = a0 + ad; e0 = e0 > 0.f ? e0 : 0.2f * e0;
            float e1 = a1 + ad; e1 = e1 > 0.f ? e1 : 0.2f * e1;
            float e2 = a2 + ad; e2 = e2 > 0.f ? e2 : 0.2f * e2;
            float e3 = a3 + ad; e3 = e3 > 0.f ? e3 : 0.2f * e3;
            float w0 = j0 < m ? __expf(e0) : 0.f;
            float w1 = j1 < m ? __expf(e1) : 0.f;
            float w2 = j2 < m ? __expf(e2) : 0.f;
            float w3 = j3 < m ? __expf(e3) : 0.f;
            acc.x = fmaf(w0, h0.x, acc.x); acc.y = fmaf(w0, h0.y, acc.y);
            acc.z = fmaf(w0, h0.z, acc.z); acc.w = fmaf(w0, h0.w, acc.w); wsum += w0;
            acc.x = fmaf(w1, h1.x, acc.x); acc.y = fmaf(w1, h1.y, acc.y);
            acc.z = fmaf(w1, h1.z, acc.z); acc.w = fmaf(w1, h1.w, acc.w); wsum += w1;
            acc.x = fmaf(w2, h2.x, acc.x); acc.y = fmaf(w2, h2.y, acc.y);
            acc.z = fmaf(w2, h2.z, acc.z); acc.w = fmaf(w2, h2.w, acc.w); wsum += w2;
            acc.x = fmaf(w3, h3.x, acc.x); acc.y = fmaf(w3, h3.y, acc.y);
            acc.z = fmaf(w3, h3.z, acc.z); acc.w = fmaf(w3, h3.w, acc.w); wsum += w3;
        }
        for (; k < steps; ++k) {
            int j = 4 * k + q;
            int i = min(j, m - 1);
            int s = __shfl(c, i);
            float4 hv = H4[s * 16 + ql];
            float a = ALs[s * 8 + hh];
            float e = a + ad; e = e > 0.f ? e : 0.2f * e;
            float w = j < m ? __expf(e) : 0.f;
            acc.x = fmaf(w, hv.x, acc.x); acc.y = fmaf(w, hv.y, acc.y);
            acc.z = fmaf(w, hv.z, acc.z); acc.w = fmaf(w, hv.w, acc.w);
            wsum += w;
        }
    }

    // merge quarters: lanes l, l^16, l^32, l^48
#pragma unroll
    for (int off = 16; off <= 32; off <<= 1) {
        acc.x += __shfl_xor(acc.x, off);
        acc.y += __shfl_xor(acc.y, off);
        acc.z += __shfl_xor(acc.z, off);
        acc.w += __shfl_xor(acc.w, off);
        wsum += __shfl_xor(wsum, off);
    }

    if (q == 0) {
        float inv = 1.f / wsum;
        float4 bv = ((const float4*)bias)[ql];
        float4 o;
        o.x = acc.x * inv + bv.x; o.x = o.x > 0.f ? o.x : expm1f(o.x);
        o.y = acc.y * inv + bv.y; o.y = o.y > 0.f ? o.y : expm1f(o.y);
        o.z = acc.z * inv + bv.z; o.z = o.z > 0.f ? o.z : expm1f(o.z);
        o.w = acc.w * inv + bv.w; o.w = o.w > 0.f ? o.w : expm1f(o.w);
        ((float4*)Out)[d * 16 + ql] = o;
    }
}

// ---------------- global mean pool (batch is sorted) ----------------

__global__ void pool_kernel(const float* __restrict__ H, const int* __restrict__ batch,
                            float* __restrict__ sums, float* __restrict__ cnt, int n) {
    int gw = (int)((blockIdx.x * blockDim.x + threadIdx.x) >> 6);
    int lane = threadIdx.x & 63;
    int n0 = gw * 64;
    if (n0 >= n) return;
    int n1 = min(n0 + 64, n);
    int curb = batch[n0];
    float local = 0.f, c_local = 0.f;
    for (int i = n0; i < n1; ++i) {
        int b = batch[i];
        if (b != curb) {
            atomicAdd(&sums[curb * 64 + lane], local);
            if (lane == 0) atomicAdd(&cnt[curb], c_local);
            local = 0.f;
            c_local = 0.f;
            curb = b;
        }
        local += H[(size_t)i * 64 + lane];
        c_local += 1.f;
    }
    atomicAdd(&sums[curb * 64 + lane], local);
    if (lane == 0) atomicAdd(&cnt[curb], c_local);
}

__global__ void final_kernel(const float* __restrict__ sums, const float* __restrict__ cnt,
                             const float* __restrict__ W, const float* __restrict__ b,
                             float* __restrict__ out) {
    int t = blockIdx.x * blockDim.x + threadIdx.x;
    if (t >= GG * NCLS) return;
    int g = t / NCLS, k = t % NCLS;
    float c = cnt[g];
    if (c < 1.f) c = 1.f;
    float inv = 1.f / c;
    float acc = b[k];
#pragma unroll
    for (int cc = 0; cc < 64; ++cc)
        acc = fmaf(sums[g * 64 + cc] * inv, W[cc * NCLS + k], acc);
    out[t] = acc;
}

// ---------------- launch ----------------

extern "C" void kernel_launch(void* const* d_in, const int* in_sizes, int n_in,
                              void* d_out, int out_size, void* d_ws, size_t ws_size,
                              hipStream_t stream) {
    const float* x    = (const float*)d_in[0];
    const int*   ei   = (const int*)d_in[1];   // [2,E]: src = ei, dst = ei+EE
    const int*   batch = (const int*)d_in[2];
    const float* W1 = (const float*)d_in[3];
    const float* a1s = (const float*)d_in[4];
    const float* a1d = (const float*)d_in[5];
    const float* b1 = (const float*)d_in[6];
    const float* W2 = (const float*)d_in[7];
    const float* a2s = (const float*)d_in[8];
    const float* a2d = (const float*)d_in[9];
    const float* b2 = (const float*)d_in[10];
    const float* W3 = (const float*)d_in[11];
    const float* a3s = (const float*)d_in[12];
    const float* a3d = (const float*)d_in[13];
    const float* b3 = (const float*)d_in[14];
    const float* linW = (const float*)d_in[15];
    const float* linb = (const float*)d_in[16];
    float* out = (float*)d_out;

    char* ws = (char*)d_ws;
    size_t off = 0;
    auto alloc = [&](size_t bytes) -> void* {
        void* p = ws + off;
        off = (off + bytes + 255) & ~(size_t)255;
        return p;
    };
    float* hA     = (float*)alloc((size_t)NN * 64 * 4);
    float* hB     = (float*)alloc((size_t)NN * 64 * 4);
    float* ALs    = (float*)alloc((size_t)NN * 8 * 4);
    float* ALd    = (float*)alloc((size_t)NN * 8 * 4);
    int*   rowptr = (int*)alloc((size_t)(NN + 1) * 4);
    int*   bcnt   = (int*)alloc(256 * 4);
    int*   bfill  = (int*)alloc(256 * 4);
    int*   bbase  = (int*)alloc(257 * 4);
    int*   bsrc   = (int*)alloc((size_t)EE * 4);
    int*   bdst   = (int*)alloc((size_t)EE * 4);
    int*   col    = (int*)alloc((size_t)EE * 4);
    float* sums   = (float*)alloc((size_t)(GG * 64 + GG) * 4);
    float* gcnt   = sums + GG * 64;

    const int NBLK = (NN + 255) / 256;
    const int EB4 = (EE + EPB - 1) / EPB;

    hipMemsetAsync(bcnt, 0, 256 * 4, stream);
    hipMemsetAsync(bfill, 0, 256 * 4, stream);
    bhist_kernel<<<EB4, 256, 0, stream>>>(ei + EE, bcnt, EE);
    bscan_kernel<<<1, 256, 0, stream>>>(bcnt, bbase);
    bscatter_kernel<<<EB4, 256, 0, stream>>>(ei, ei + EE, bfill, bbase, bsrc, bdst, EE);
    bsort_kernel<<<NB, 512, 0, stream>>>(bsrc, bdst, bbase, rowptr, col);

    const int GB = NN / 16;
    const int AB = (NN + 3) / 4;

    gemm_al_kernel<128><<<GB, 256, 0, stream>>>(x, W1, a1s, a1d, hA, ALs, ALd, NN);
    agg_kernel<<<AB, 256, 0, stream>>>(hA, ALs, ALd, rowptr, col, b1, hB, NN);

    gemm_al_kernel<64><<<GB, 256, 0, stream>>>(hB, W2, a2s, a2d, hA, ALs, ALd, NN);
    agg_kernel<<<AB, 256, 0, stream>>>(hA, ALs, ALd, rowptr, col, b2, hB, NN);

    gemm_al_kernel<64><<<GB, 256, 0, stream>>>(hB, W3, a3s, a3d, hA, ALs, ALd, NN);
    agg_kernel<<<AB, 256, 0, stream>>>(hA, ALs, ALd, rowptr, col, b3, hB, NN);

    hipMemsetAsync(sums, 0, (size_t)(GG * 64 + GG) * 4, stream);
    pool_kernel<<<NBLK, 256, 0, stream>>>(hB, batch, sums, gcnt, NN);
    final_kernel<<<3, 256, 0, stream>>>(sums, gcnt, linW, linb, out);
}